// Round 8
// baseline (248.787 us; speedup 1.0000x reference)
//
#include <hip/hip_runtime.h>
#include <hip/hip_cooperative_groups.h>

namespace cg = cooperative_groups;

// Problem constants (B=32, N=256, D=256 -> M=8192)
#define M_ROWS 8192
#define D_DIM  256
#define BM     256                // block tile rows (i / audio)
#define BN     128                // block tile cols (j / visual)
#define NBI    (M_ROWS / BM)      // 32 i-tiles
#define NBJ    (M_ROWS / BN)      // 64 j-tiles
#define NJOBS  (NBI * NBJ)        // 2048 gemm tile jobs

// Fold 1/TEMP * log2(e) into normalization: acc = log2(e)*sim/TEMP, e = exp2(acc)
#define ALPHA  4.53982478f        // sqrt(log2(e)/0.07)

// fp8 fragment-order layout:
//   8-B chunk index = tile16 * 512 + k32 * 64 + lane,   lane = quad*16 + l16
//   chunk contents  = row (tile16*16 + l16), k = k32*32 + quad*8 .. +7  (8 x e4m3)
// => an MFMA A/B fragment load (16x16x32_fp8) is 64 lanes x 8 B fully contiguous.

typedef __attribute__((ext_vector_type(4))) float  floatx4;  // MFMA C/D

__device__ inline unsigned short f2bf(float f) {
    union { float f; unsigned int u; } v; v.f = f;
    unsigned int u = v.u;
    u = (u + 0x7fffu + ((u >> 16) & 1u)) >> 16;   // RNE
    return (unsigned short)u;
}

__device__ inline float bf2f(unsigned short b) {
    union { unsigned int u; float f; } v; v.u = (unsigned int)b << 16;
    return v.f;
}

__device__ inline float fast_exp2(float x) {
#if __has_builtin(__builtin_amdgcn_exp2f)
    return __builtin_amdgcn_exp2f(x);
#else
    return exp2f(x);
#endif
}

// Single fused cooperative kernel. Phases separated by grid.sync():
//  1) L2-normalize + ALPHA scale + fp8 e4m3 fragment-order emit
//  2) fp8 MFMA gemm + exp2 + (total,class1) per-tile partials (R7 body)
//  3) reduce partials over slabs -> per-reduce-block (sum,count)
//  4) block 0: final scalar
__global__ __launch_bounds__(256, 2) void fused_kernel(
    const float* __restrict__ af, const float* __restrict__ vf,
    const int* __restrict__ la, const int* __restrict__ lv,
    unsigned char* __restrict__ aB, unsigned char* __restrict__ vB,
    float* __restrict__ rowPart, float* __restrict__ colPart,
    float* __restrict__ blockPart, float* __restrict__ out)
{
    __shared__ unsigned short tileS[16 * 264];   // 8.25 KB arena (all phases)
    __shared__ float red[4][2];
    cg::grid_group grid = cg::this_grid();

    const int tid  = threadIdx.x;
    const int bid  = blockIdx.x;
    const int G    = gridDim.x;
    const int wave = tid >> 6, lane = tid & 63;
    const int quad = lane >> 4, l16 = lane & 15;

    // ================= Phase 1: normalize -> fp8 fragment order =================
    for (int u = bid; u < 1024; u += G) {
        const bool isA = u < 512;
        const int T = isA ? u : u - 512;     // tile16 index 0..511
        const float* src = (isA ? af : vf) + (size_t)T * 16 * D_DIM;
        unsigned char* dst = (isA ? aB : vB) + (size_t)T * 4096;  // 512 chunks x 8 B

        const int row = tid >> 4, c = tid & 15;
        const float* p = src + row * D_DIM + c * 16;
        float4 x0 = ((const float4*)p)[0], x1 = ((const float4*)p)[1];
        float4 x2 = ((const float4*)p)[2], x3 = ((const float4*)p)[3];
        float ss = x0.x*x0.x + x0.y*x0.y + x0.z*x0.z + x0.w*x0.w
                 + x1.x*x1.x + x1.y*x1.y + x1.z*x1.z + x1.w*x1.w
                 + x2.x*x2.x + x2.y*x2.y + x2.z*x2.z + x2.w*x2.w
                 + x3.x*x3.x + x3.y*x3.y + x3.z*x3.z + x3.w*x3.w;
        #pragma unroll
        for (int m = 1; m < 16; m <<= 1) ss += __shfl_xor(ss, m, 64);
        float scale = ALPHA / fmaxf(sqrtf(ss), 1e-12f);

        unsigned short* q = tileS + row * 264 + c * 16;
        ushort4 o0, o1, o2, o3;
        o0.x = f2bf(x0.x*scale); o0.y = f2bf(x0.y*scale); o0.z = f2bf(x0.z*scale); o0.w = f2bf(x0.w*scale);
        o1.x = f2bf(x1.x*scale); o1.y = f2bf(x1.y*scale); o1.z = f2bf(x1.z*scale); o1.w = f2bf(x1.w*scale);
        o2.x = f2bf(x2.x*scale); o2.y = f2bf(x2.y*scale); o2.z = f2bf(x2.z*scale); o2.w = f2bf(x2.w*scale);
        o3.x = f2bf(x3.x*scale); o3.y = f2bf(x3.y*scale); o3.z = f2bf(x3.z*scale); o3.w = f2bf(x3.w*scale);
        ((ushort4*)q)[0] = o0; ((ushort4*)q)[1] = o1;
        ((ushort4*)q)[2] = o2; ((ushort4*)q)[3] = o3;
        __syncthreads();

        #pragma unroll
        for (int s = 0; s < 2; ++s) {
            const int ch  = tid + s * 256;           // 0..511
            const int cl16 = ch & 15, cq = (ch >> 4) & 3, ck = ch >> 6;
            const unsigned short* rp = &tileS[cl16 * 264 + ck * 32 + cq * 8];
            float f0 = bf2f(rp[0]), f1 = bf2f(rp[1]), f2 = bf2f(rp[2]), f3 = bf2f(rp[3]);
            float f4 = bf2f(rp[4]), f5 = bf2f(rp[5]), f6 = bf2f(rp[6]), f7 = bf2f(rp[7]);
            int p0 = __builtin_amdgcn_cvt_pk_fp8_f32(f0, f1, 0, false);
            p0     = __builtin_amdgcn_cvt_pk_fp8_f32(f2, f3, p0, true);
            int p1 = __builtin_amdgcn_cvt_pk_fp8_f32(f4, f5, 0, false);
            p1     = __builtin_amdgcn_cvt_pk_fp8_f32(f6, f7, p1, true);
            int2 outv; outv.x = p0; outv.y = p1;
            *(int2*)(dst + (size_t)ch * 8) = outv;
        }
        __syncthreads();                             // tileS reused next unit
    }
    grid.sync();

    // ================= Phase 2: fp8 gemm + exp2 + partials =================
    float* rowbuf = (float*)tileS;                   // 512 floats
    float* colbuf = (float*)tileS + 512;             // 1024 floats

    for (int job = bid; job < NJOBS; job += G) {
        // supertile swizzle: 256-job groups cover 16x16 tile regions (L2 locality)
        const int super = job >> 8;                  // 0..7
        const int inner = job & 255;
        const int bx = (super & 1) * 16 + (inner & 15);    // 0..31 (i-tile)
        const int by = (super >> 1) * 16 + (inner >> 4);   // 0..63 (j-tile)
        const int i0 = bx * BM, j0 = by * BN;

        const unsigned char* Abase = aB + ((size_t)(bx * 16 + wave * 4) * 512 + lane) * 8;
        const unsigned char* Vbase = vB + ((size_t)(by * 8) * 512 + lane) * 8;

        floatx4 acc[4][8] = {};
        long long afr[3][4], bfr[3][8];

        #pragma unroll
        for (int s = 0; s < 2; ++s) {               // preload stages 0,1
            #pragma unroll
            for (int it = 0; it < 4; ++it)
                afr[s][it] = *(const long long*)(Abase + it * 4096 + s * 512);
            #pragma unroll
            for (int jt = 0; jt < 8; ++jt)
                bfr[s][jt] = *(const long long*)(Vbase + jt * 4096 + s * 512);
        }

        #pragma unroll
        for (int k32 = 0; k32 < 8; ++k32) {         // 8 MFMA K=32 steps (K=256)
            const int cur = k32 % 3;
            if (k32 < 6) {
                const int nx = (k32 + 2) % 3;
                const size_t ko = (size_t)(k32 + 2) * 512;
                #pragma unroll
                for (int it = 0; it < 4; ++it)
                    afr[nx][it] = *(const long long*)(Abase + it * 4096 + ko);
                #pragma unroll
                for (int jt = 0; jt < 8; ++jt)
                    bfr[nx][jt] = *(const long long*)(Vbase + jt * 4096 + ko);
            }
            #pragma unroll
            for (int it = 0; it < 4; ++it)
                #pragma unroll
                for (int jt = 0; jt < 8; ++jt)
                    acc[it][jt] = __builtin_amdgcn_mfma_f32_16x16x32_fp8_fp8(
                        afr[cur][it], bfr[cur][jt], acc[it][jt], 0, 0, 0);
        }

        // epilogue: exp2 + (total, class1); C/D: col = l16, row = quad*4 + r
        const int baseRow = i0 + wave * 64;
        float maf[4][4];
        #pragma unroll
        for (int it = 0; it < 4; ++it)
            #pragma unroll
            for (int r = 0; r < 4; ++r)
                maf[it][r] = (float)la[baseRow + it * 16 + quad * 4 + r];
        float mvf[8];
        #pragma unroll
        for (int jt = 0; jt < 8; ++jt)
            mvf[jt] = (float)lv[j0 + jt * 16 + l16];

        float rT[4][4] = {}, r1[4][4] = {};
        float cT[8] = {}, c1[8] = {};
        #pragma unroll
        for (int it = 0; it < 4; ++it) {
            #pragma unroll
            for (int jt = 0; jt < 8; ++jt) {
                #pragma unroll
                for (int r = 0; r < 4; ++r) {
                    float e = fast_exp2(acc[it][jt][r]);
                    rT[it][r] += e;
                    r1[it][r] = fmaf(mvf[jt], e, r1[it][r]);
                    cT[jt] += e;
                    c1[jt] = fmaf(maf[it][r], e, c1[jt]);
                }
            }
        }

        #pragma unroll
        for (int jt = 0; jt < 8; ++jt) {
            float t0 = cT[jt], t1 = c1[jt];
            t0 += __shfl_xor(t0, 16, 64); t0 += __shfl_xor(t0, 32, 64);
            t1 += __shfl_xor(t1, 16, 64); t1 += __shfl_xor(t1, 32, 64);
            cT[jt] = t0; c1[jt] = t1;
        }

        #pragma unroll
        for (int it = 0; it < 4; ++it) {
            #pragma unroll
            for (int r = 0; r < 4; ++r) {
                float s0 = rT[it][r], s1 = r1[it][r];
                #pragma unroll
                for (int m = 1; m < 16; m <<= 1) {
                    s0 += __shfl_xor(s0, m, 64);
                    s1 += __shfl_xor(s1, m, 64);
                }
                if (l16 == 0) {
                    int rl = wave * 64 + it * 16 + quad * 4 + r;   // 0..255
                    rowbuf[rl * 2 + 0] = s0;
                    rowbuf[rl * 2 + 1] = s1;
                }
            }
        }
        if (quad == 0) {
            #pragma unroll
            for (int jt = 0; jt < 8; ++jt) {
                colbuf[(wave * 2 + 0) * BN + jt * 16 + l16] = cT[jt];
                colbuf[(wave * 2 + 1) * BN + jt * 16 + l16] = c1[jt];
            }
        }
        __syncthreads();

        *(float2*)&rowPart[((size_t)by * M_ROWS + i0 + tid) * 2] = ((float2*)rowbuf)[tid];
        {
            const int rl  = tid >> 1;      // 0..127
            const int cls = tid & 1;
            float s = colbuf[(0 * 2 + cls) * BN + rl] + colbuf[(1 * 2 + cls) * BN + rl]
                    + colbuf[(2 * 2 + cls) * BN + rl] + colbuf[(3 * 2 + cls) * BN + rl];
            colPart[((size_t)bx * M_ROWS + j0 + rl) * 2 + cls] = s;
        }
        __syncthreads();                   // rowbuf/colbuf reused next job
    }
    grid.sync();

    // ================= Phase 3: slab reduction + log terms =================
    for (int rb = bid; rb < 64; rb += G) {
        const bool aside = rb < 32;
        const int idx = (aside ? rb : rb - 32) * 256 + tid;
        const float* part = aside ? rowPart : colPart;
        const int* lab = aside ? la : lv;
        const int nb = aside ? NBJ : NBI;

        float tot = 0.f, c1 = 0.f;
        #pragma unroll 4
        for (int b = 0; b < nb; ++b) {
            float2 p = *(const float2*)(part + ((size_t)b * M_ROWS + idx) * 2);
            tot += p.x; c1 += p.y;
        }
        float num = lab[idx] ? c1 : 0.1f * (tot - c1);
        float lg = 0.f, cnt = 0.f;
        if (num > 0.f) { lg = logf((num + 1e-8f) / (tot + 1e-8f)); cnt = 1.f; }

        #pragma unroll
        for (int m = 1; m < 64; m <<= 1) {
            lg  += __shfl_xor(lg,  m, 64);
            cnt += __shfl_xor(cnt, m, 64);
        }
        if (lane == 0) { red[wave][0] = lg; red[wave][1] = cnt; }
        __syncthreads();
        if (tid == 0) {
            blockPart[rb * 2 + 0] = red[0][0] + red[1][0] + red[2][0] + red[3][0];
            blockPart[rb * 2 + 1] = red[0][1] + red[1][1] + red[2][1] + red[3][1];
        }
        __syncthreads();                   // red reused next rb
    }
    grid.sync();

    // ================= Phase 4: final scalar (block 0, wave 0) =================
    if (bid == 0 && tid < 64) {
        float lg  = blockPart[tid * 2 + 0];
        float cnt = blockPart[tid * 2 + 1];
        #pragma unroll
        for (int m = 1; m < 32; m <<= 1) {
            lg  += __shfl_xor(lg,  m, 64);
            cnt += __shfl_xor(cnt, m, 64);
        }
        float sA = __shfl(lg, 0, 64),  cA = __shfl(cnt, 0, 64);
        float sV = __shfl(lg, 32, 64), cV = __shfl(cnt, 32, 64);
        if (tid == 0) {
            float lossA = -sA / fmaxf(cA, 1.f);
            float lossV = -sV / fmaxf(cV, 1.f);
            out[0] = 0.5f * (lossA + lossV);
        }
    }
}

extern "C" void kernel_launch(void* const* d_in, const int* in_sizes, int n_in,
                              void* d_out, int out_size, void* d_ws, size_t ws_size,
                              hipStream_t stream)
{
    const float* af = (const float*)d_in[0];
    const float* vf = (const float*)d_in[1];
    const int*   la = (const int*)d_in[2];
    const int*   lv = (const int*)d_in[3];
    float* out = (float*)d_out;

    char* ws = (char*)d_ws;
    unsigned char* aB = (unsigned char*)ws;                            // 2 MiB (fp8 fragment order)
    unsigned char* vB = (unsigned char*)(ws + 2ull * 1024 * 1024);     // 2 MiB
    float* rowPart   = (float*)(ws +  4ull * 1024 * 1024);             // 4 MiB [64][8192][2]
    float* colPart   = (float*)(ws +  8ull * 1024 * 1024);             // 2 MiB [32][8192][2]
    float* blockPart = (float*)(ws + 10ull * 1024 * 1024);             // 512 B

    // co-residency-safe grid (query, no static caching; same work every call)
    int nb = 0;
    hipOccupancyMaxActiveBlocksPerMultiprocessor(&nb, fused_kernel, 256, 0);
    if (nb < 1) nb = 1;
    long long g = (long long)nb * 256;
    if (g > 512) g = 512;

    void* args[] = { (void*)&af, (void*)&vf, (void*)&la, (void*)&lv,
                     (void*)&aB, (void*)&vB, (void*)&rowPart, (void*)&colPart,
                     (void*)&blockPart, (void*)&out };
    hipLaunchCooperativeKernel((void*)fused_kernel, dim3((unsigned)g), dim3(256),
                               args, 0, stream);
}

// Round 9
// 130.416 us; speedup vs baseline: 1.9076x; 1.9076x over previous
//
#include <hip/hip_runtime.h>

// Problem constants (B=32, N=256, D=256 -> M=8192)
#define M_ROWS 8192
#define D_DIM  256
#define BM     128                // block tile rows (i / audio)
#define BN     128                // block tile cols (j / visual)
#define NBI    (M_ROWS / BM)      // 64 i-tiles
#define NBJ    (M_ROWS / BN)      // 64 j-tiles
#define NJOBS  (NBI * NBJ)        // 4096 gemm blocks

// Fold 1/TEMP * log2(e) into normalization: acc = log2(e)*sim/TEMP, e = exp2(acc)
#define ALPHA  4.53982478f        // sqrt(log2(e)/0.07)

// fp8 fragment-order layout:
//   8-B chunk index = tile16 * 512 + k32 * 64 + lane,   lane = quad*16 + l16
//   chunk contents  = row (tile16*16 + l16), k = k32*32 + quad*8 .. +7  (8 x e4m3)
// => an MFMA A/B fragment load (16x16x32_fp8) is 64 lanes x 8 B fully contiguous.

typedef __attribute__((ext_vector_type(4))) float  floatx4;  // MFMA C/D

__device__ inline unsigned short f2bf(float f) {
    union { float f; unsigned int u; } v; v.f = f;
    unsigned int u = v.u;
    u = (u + 0x7fffu + ((u >> 16) & 1u)) >> 16;   // RNE
    return (unsigned short)u;
}

__device__ inline float bf2f(unsigned short b) {
    union { unsigned int u; float f; } v; v.u = (unsigned int)b << 16;
    return v.f;
}

__device__ inline float fast_exp2(float x) {
#if __has_builtin(__builtin_amdgcn_exp2f)
    return __builtin_amdgcn_exp2f(x);
#else
    return exp2f(x);
#endif
}

// Kernel 1: L2-normalize 16 rows per block, scale by ALPHA, emit fp8 e4m3 in
// fragment order via padded LDS transpose. Block 0 also zeroes the finalize
// accumulators (4 floats + int counter) used by the merged reduce+finalize.
__global__ __launch_bounds__(256) void normalize_kernel(
    const float* __restrict__ af, const float* __restrict__ vf,
    unsigned char* __restrict__ aB, unsigned char* __restrict__ vB,
    float* __restrict__ glob)
{
    __shared__ unsigned short tileS[16 * 264];   // 8.25 KB

    if (blockIdx.x == 0) {
        if (threadIdx.x < 4) glob[threadIdx.x] = 0.f;
        if (threadIdx.x == 4) ((int*)glob)[4] = 0;
    }

    const int b = blockIdx.x;            // 0..1023
    const bool isA = b < 512;
    const int T = isA ? b : b - 512;     // tile16 index 0..511
    const float* src = (isA ? af : vf) + (size_t)T * 16 * D_DIM;
    unsigned char* dst = (isA ? aB : vB) + (size_t)T * 4096;  // 512 chunks x 8 B

    const int t = threadIdx.x;
    const int row = t >> 4, c = t & 15;  // 16 threads per row, 16 elems each

    const float* p = src + row * D_DIM + c * 16;
    float4 x0 = ((const float4*)p)[0], x1 = ((const float4*)p)[1];
    float4 x2 = ((const float4*)p)[2], x3 = ((const float4*)p)[3];
    float ss = x0.x*x0.x + x0.y*x0.y + x0.z*x0.z + x0.w*x0.w
             + x1.x*x1.x + x1.y*x1.y + x1.z*x1.z + x1.w*x1.w
             + x2.x*x2.x + x2.y*x2.y + x2.z*x2.z + x2.w*x2.w
             + x3.x*x3.x + x3.y*x3.y + x3.z*x3.z + x3.w*x3.w;
    #pragma unroll
    for (int m = 1; m < 16; m <<= 1) ss += __shfl_xor(ss, m, 64);
    float scale = ALPHA / fmaxf(sqrtf(ss), 1e-12f);

    unsigned short* q = tileS + row * 264 + c * 16;
    ushort4 o0, o1, o2, o3;
    o0.x = f2bf(x0.x*scale); o0.y = f2bf(x0.y*scale); o0.z = f2bf(x0.z*scale); o0.w = f2bf(x0.w*scale);
    o1.x = f2bf(x1.x*scale); o1.y = f2bf(x1.y*scale); o1.z = f2bf(x1.z*scale); o1.w = f2bf(x1.w*scale);
    o2.x = f2bf(x2.x*scale); o2.y = f2bf(x2.y*scale); o2.z = f2bf(x2.z*scale); o2.w = f2bf(x2.w*scale);
    o3.x = f2bf(x3.x*scale); o3.y = f2bf(x3.y*scale); o3.z = f2bf(x3.z*scale); o3.w = f2bf(x3.w*scale);
    ((ushort4*)q)[0] = o0; ((ushort4*)q)[1] = o1;
    ((ushort4*)q)[2] = o2; ((ushort4*)q)[3] = o3;
    __syncthreads();

    #pragma unroll
    for (int s = 0; s < 2; ++s) {
        const int ch  = t + s * 256;             // 0..511
        const int l16 = ch & 15, quad = (ch >> 4) & 3, k32 = ch >> 6;
        const unsigned short* rp = &tileS[l16 * 264 + k32 * 32 + quad * 8];
        float f0 = bf2f(rp[0]), f1 = bf2f(rp[1]), f2 = bf2f(rp[2]), f3 = bf2f(rp[3]);
        float f4 = bf2f(rp[4]), f5 = bf2f(rp[5]), f6 = bf2f(rp[6]), f7 = bf2f(rp[7]);
        int p0 = __builtin_amdgcn_cvt_pk_fp8_f32(f0, f1, 0, false);
        p0     = __builtin_amdgcn_cvt_pk_fp8_f32(f2, f3, p0, true);
        int p1 = __builtin_amdgcn_cvt_pk_fp8_f32(f4, f5, 0, false);
        p1     = __builtin_amdgcn_cvt_pk_fp8_f32(f6, f7, p1, true);
        int2 outv; outv.x = p0; outv.y = p1;
        *(int2*)(dst + (size_t)ch * 8) = outv;
    }
}

// Kernel 2: fused GEMM (acc = log2e*sim/T) in fp8, exp2, (total,class1) sums.
// 3 waves/SIMD occupancy target: wave tile 32x128 (acc[2][8] = 64 AGPR),
// 3-stage fp8 register ring (~60 VGPR), __launch_bounds__(256,3).
// Block 256 = 4 waves; block tile 128x128; no LDS/barriers until epilogue.
__global__ __launch_bounds__(256, 3) void gemm_loss_kernel(
    const unsigned char* __restrict__ aB, const unsigned char* __restrict__ vB,
    const int* __restrict__ la, const int* __restrict__ lv,
    float* __restrict__ rowPart, float* __restrict__ colPart)
{
    const int tid  = threadIdx.x;
    const int wave = tid >> 6, lane = tid & 63;
    const int quad = lane >> 4, l16 = lane & 15;

    // supertile swizzle: 16 supers x 256 inner -> 16x16 tile regions (L2 locality)
    const int super = blockIdx.x >> 8;          // 0..15
    const int inner = blockIdx.x & 255;
    const int bx = (super & 3) * 16 + (inner & 15);    // 0..63 (i-tile)
    const int by = (super >> 2) * 16 + (inner >> 4);   // 0..63 (j-tile)
    const int i0 = bx * BM, j0 = by * BN;

    // fragment bases: tile16 stride = 512 chunks * 8 B = 4096 B; k32 stride = 512 B
    const unsigned char* Abase = aB + ((size_t)(bx * 8 + wave * 2) * 512 + lane) * 8;
    const unsigned char* Vbase = vB + ((size_t)(by * 8) * 512 + lane) * 8;

    floatx4 acc[2][8] = {};
    long long afr[3][2], bfr[3][8];

    #pragma unroll
    for (int s = 0; s < 2; ++s) {               // preload stages 0,1
        #pragma unroll
        for (int it = 0; it < 2; ++it)
            afr[s][it] = *(const long long*)(Abase + it * 4096 + s * 512);
        #pragma unroll
        for (int jt = 0; jt < 8; ++jt)
            bfr[s][jt] = *(const long long*)(Vbase + jt * 4096 + s * 512);
    }

    #pragma unroll
    for (int k32 = 0; k32 < 8; ++k32) {         // 8 MFMA K=32 steps (K=256)
        const int cur = k32 % 3;
        if (k32 < 6) {
            const int nx = (k32 + 2) % 3;
            const size_t ko = (size_t)(k32 + 2) * 512;
            #pragma unroll
            for (int it = 0; it < 2; ++it)
                afr[nx][it] = *(const long long*)(Abase + it * 4096 + ko);
            #pragma unroll
            for (int jt = 0; jt < 8; ++jt)
                bfr[nx][jt] = *(const long long*)(Vbase + jt * 4096 + ko);
        }
        #pragma unroll
        for (int it = 0; it < 2; ++it)
            #pragma unroll
            for (int jt = 0; jt < 8; ++jt)
                acc[it][jt] = __builtin_amdgcn_mfma_f32_16x16x32_fp8_fp8(
                    afr[cur][it], bfr[cur][jt], acc[it][jt], 0, 0, 0);
    }

    // ---- epilogue: exp2 + (total, class1); C/D: col = l16, row = quad*4 + r
    const int baseRow = i0 + wave * 32;
    float maf[2][4];
    #pragma unroll
    for (int it = 0; it < 2; ++it)
        #pragma unroll
        for (int r = 0; r < 4; ++r)
            maf[it][r] = (float)la[baseRow + it * 16 + quad * 4 + r];
    float mvf[8];
    #pragma unroll
    for (int jt = 0; jt < 8; ++jt)
        mvf[jt] = (float)lv[j0 + jt * 16 + l16];

    float rT[2][4] = {}, r1[2][4] = {};
    float cT[8] = {}, c1[8] = {};
    #pragma unroll
    for (int it = 0; it < 2; ++it) {
        #pragma unroll
        for (int jt = 0; jt < 8; ++jt) {
            #pragma unroll
            for (int r = 0; r < 4; ++r) {
                float e = fast_exp2(acc[it][jt][r]);
                rT[it][r] += e;
                r1[it][r] = fmaf(mvf[jt], e, r1[it][r]);
                cT[jt] += e;
                c1[jt] = fmaf(maf[it][r], e, c1[jt]);
            }
        }
    }

    // col sums: reduce over quads within wave (register-only)
    #pragma unroll
    for (int jt = 0; jt < 8; ++jt) {
        float t0 = cT[jt], t1 = c1[jt];
        t0 += __shfl_xor(t0, 16, 64); t0 += __shfl_xor(t0, 32, 64);
        t1 += __shfl_xor(t1, 16, 64); t1 += __shfl_xor(t1, 32, 64);
        cT[jt] = t0; c1[jt] = t1;
    }

    __shared__ float rowbuf[2 * BM];            // [128][2] = 1 KB
    __shared__ float colbuf[8 * BN];            // [4 waves][2][128] = 4 KB

    // row sums: reduce over the quad's 16 lanes (cols), stage in LDS
    #pragma unroll
    for (int it = 0; it < 2; ++it) {
        #pragma unroll
        for (int r = 0; r < 4; ++r) {
            float s0 = rT[it][r], s1 = r1[it][r];
            #pragma unroll
            for (int m = 1; m < 16; m <<= 1) {
                s0 += __shfl_xor(s0, m, 64);
                s1 += __shfl_xor(s1, m, 64);
            }
            if (l16 == 0) {
                int rl = wave * 32 + it * 16 + quad * 4 + r;   // 0..127
                rowbuf[rl * 2 + 0] = s0;
                rowbuf[rl * 2 + 1] = s1;
            }
        }
    }
    if (quad == 0) {
        #pragma unroll
        for (int jt = 0; jt < 8; ++jt) {
            colbuf[(wave * 2 + 0) * BN + jt * 16 + l16] = cT[jt];
            colbuf[(wave * 2 + 1) * BN + jt * 16 + l16] = c1[jt];
        }
    }
    __syncthreads();

    // coalesced per-block partial writes (256 floats each)
    {
        const int rl  = tid >> 1;      // 0..127
        const int cls = tid & 1;
        rowPart[((size_t)by * M_ROWS + i0 + rl) * 2 + cls] = rowbuf[rl * 2 + cls];
        float s = colbuf[(0 * 2 + cls) * BN + rl] + colbuf[(1 * 2 + cls) * BN + rl]
                + colbuf[(2 * 2 + cls) * BN + rl] + colbuf[(3 * 2 + cls) * BN + rl];
        colPart[((size_t)bx * M_ROWS + j0 + rl) * 2 + cls] = s;
    }
}

// Kernel 3: reduce partials over 64 slabs, per-row/col log terms, then merged
// finalize: per-block (sum,count) -> device atomicAdd; last block (atomic
// counter) computes the final scalar. Blocks 0..31 = rows, 32..63 = cols.
// glob: [sumA, cntA, sumV, cntV, (int)counter] - zeroed by normalize block 0.
__global__ __launch_bounds__(256) void reduce_kernel(
    const float* __restrict__ rowPart, const float* __restrict__ colPart,
    const int* __restrict__ la, const int* __restrict__ lv,
    float* __restrict__ glob, float* __restrict__ out)
{
    const int bid = blockIdx.x;
    const bool aside = bid < 32;
    const int idx = (aside ? bid : bid - 32) * 256 + threadIdx.x;   // row or col index
    const float* part = aside ? rowPart : colPart;
    const int* lab = aside ? la : lv;

    float tot = 0.f, c1 = 0.f;
    #pragma unroll 4
    for (int b = 0; b < 64; ++b) {
        float2 p = *(const float2*)(part + ((size_t)b * M_ROWS + idx) * 2);
        tot += p.x; c1 += p.y;
    }
    float num = lab[idx] ? c1 : 0.1f * (tot - c1);
    float lg = 0.f, cnt = 0.f;
    if (num > 0.f) { lg = logf((num + 1e-8f) / (tot + 1e-8f)); cnt = 1.f; }

    #pragma unroll
    for (int m = 1; m < 64; m <<= 1) {
        lg  += __shfl_xor(lg,  m, 64);
        cnt += __shfl_xor(cnt, m, 64);
    }
    __shared__ float red[4][2];
    const int w = threadIdx.x >> 6, ln = threadIdx.x & 63;
    if (ln == 0) { red[w][0] = lg; red[w][1] = cnt; }
    __syncthreads();
    if (threadIdx.x == 0) {
        float slg  = red[0][0] + red[1][0] + red[2][0] + red[3][0];
        float scnt = red[0][1] + red[1][1] + red[2][1] + red[3][1];
        float* base = glob + (aside ? 0 : 2);
        atomicAdd(&base[0], slg);
        atomicAdd(&base[1], scnt);
        __threadfence();
        int old = atomicAdd((int*)glob + 4, 1);
        if (old == 63) {
            __threadfence();
            float sA = atomicAdd(&glob[0], 0.f);
            float cA = atomicAdd(&glob[1], 0.f);
            float sV = atomicAdd(&glob[2], 0.f);
            float cV = atomicAdd(&glob[3], 0.f);
            float lossA = -sA / fmaxf(cA, 1.f);
            float lossV = -sV / fmaxf(cV, 1.f);
            out[0] = 0.5f * (lossA + lossV);
        }
    }
}

extern "C" void kernel_launch(void* const* d_in, const int* in_sizes, int n_in,
                              void* d_out, int out_size, void* d_ws, size_t ws_size,
                              hipStream_t stream)
{
    const float* af = (const float*)d_in[0];
    const float* vf = (const float*)d_in[1];
    const int*   la = (const int*)d_in[2];
    const int*   lv = (const int*)d_in[3];
    float* out = (float*)d_out;

    char* ws = (char*)d_ws;
    unsigned char* aB = (unsigned char*)ws;                            // 2 MiB (fp8 fragment order)
    unsigned char* vB = (unsigned char*)(ws + 2ull * 1024 * 1024);     // 2 MiB
    float* rowPart   = (float*)(ws +  4ull * 1024 * 1024);             // 4 MiB [64][8192][2]
    float* colPart   = (float*)(ws +  8ull * 1024 * 1024);             // 4 MiB [64][8192][2]
    float* glob      = (float*)(ws + 12ull * 1024 * 1024);             // 4 floats + counter

    normalize_kernel<<<1024, 256, 0, stream>>>(af, vf, aB, vB, glob);
    gemm_loss_kernel<<<NJOBS, 256, 0, stream>>>(aB, vB, la, lv, rowPart, colPart);
    reduce_kernel<<<64, 256, 0, stream>>>(rowPart, colPart, la, lv, glob, out);
}